// Round 8
// baseline (798.686 us; speedup 1.0000x reference)
//
#include <hip/hip_runtime.h>
#include <math.h>

// Problem constants (B,C,H,W) = (32,256,128,128), downsample 0.5 -> (64,64)
#define NB 32
#define NC 256
#define NH 128
#define NW 128
#define NDH 64
#define NDW 64
#define NHW (NH * NW)          // 16384
#define NCELLS (NDH * NDW)     // 4096
#define OUT0_N (NB * NC * NCELLS)       // out: 33,554,432 floats
#define OUT1_BASE OUT0_N
#define OUT1_N (NB * 2 * NHW)           // offset: 1,048,576 floats
#define OUT2_BASE (OUT1_BASE + OUT1_N)  // destination: 134,217,728 floats

#define EPSF 1e-5f

typedef unsigned short u16;
typedef unsigned int   u32;

// ---- workspace layout (bytes), 16B-aligned; total ~4.5 MB ----
#define WS_META    ((size_t)0)                       // u32 [NB*NHW]   2 MB  (cell<<16 | bf16(att))
#define WS_ATTS    (WS_META + (size_t)NB*NHW*4)      // f32 [NB*NHW]   2 MB
#define WS_IASUM   (WS_ATTS + (size_t)NB*NHW*4)      // f32 [NB*NCELLS] 512 KB  (1/(asum+eps))

__device__ __forceinline__ u16 f32_to_bf16_rn(float f) {
    const u32 u = __float_as_uint(f);
    return (u16)((u + 0x7FFFu + ((u >> 16) & 1u)) >> 16);
}

// ============================================================================
// K1: read-only conv stream. One block = 64 consecutive pixels of one image.
// Reads x once (coalesced float4); emits offset output + meta + atts.
// ============================================================================
__global__ __launch_bounds__(256) void k_cells(
    const float* __restrict__ x, const float* __restrict__ cw,
    const float* __restrict__ cb, float* __restrict__ out,
    u32* __restrict__ meta, float* __restrict__ atts)
{
    __shared__ float cwS[3][NC];
    __shared__ float red[256][13];

    const int t    = threadIdx.x;
    const int blk  = blockIdx.x;
    const int b    = blk >> 8;
    const int tile = blk & 255;
    const int h    = tile >> 1;
    const int w0   = (tile & 1) << 6;
    const int pixbase = h * NW + w0;

    cwS[0][t] = cw[t];
    cwS[1][t] = cw[NC + t];
    cwS[2][t] = cw[2 * NC + t];
    __syncthreads();

    const int ct = t >> 4;            // channel group 0..15
    const int pg = (t & 15) << 2;     // pixel quad base 0..60
    const float* xb = x + (size_t)b * NC * NHW + pixbase + pg;

    float p00 = 0, p01 = 0, p02 = 0;
    float p10 = 0, p11 = 0, p12 = 0;
    float p20 = 0, p21 = 0, p22 = 0;
    float p30 = 0, p31 = 0, p32 = 0;

    #pragma unroll
    for (int i = 0; i < 16; ++i) {
        const int c = (i << 4) + ct;
        const float4 xv = *reinterpret_cast<const float4*>(xb + (size_t)c * NHW);
        const float wc0 = cwS[0][c], wc1 = cwS[1][c], wc2 = cwS[2][c];
        p00 += xv.x * wc0; p01 += xv.x * wc1; p02 += xv.x * wc2;
        p10 += xv.y * wc0; p11 += xv.y * wc1; p12 += xv.y * wc2;
        p20 += xv.z * wc0; p21 += xv.z * wc1; p22 += xv.z * wc2;
        p30 += xv.w * wc0; p31 += xv.w * wc1; p32 += xv.w * wc2;
    }

    red[t][0]  = p00; red[t][1]  = p01; red[t][2]  = p02;
    red[t][3]  = p10; red[t][4]  = p11; red[t][5]  = p12;
    red[t][6]  = p20; red[t][7]  = p21; red[t][8]  = p22;
    red[t][9]  = p30; red[t][10] = p31; red[t][11] = p32;
    __syncthreads();

    if (t < 64) {
        const int px   = t;
        const int row0 = px >> 2;
        const int col  = (px & 3) * 3;
        float s0 = 0, s1 = 0, s2 = 0;
        #pragma unroll
        for (int j = 0; j < 16; ++j) {
            const int r = row0 + (j << 4);
            s0 += red[r][col];
            s1 += red[r][col + 1];
            s2 += red[r][col + 2];
        }
        const float off0 = s0 + cb[0];
        const float off1 = s1 + cb[1];
        const float att  = expf(s2 + cb[2]);

        const float gy = (float)h * (1.0f / NH);
        const float gx = (float)(w0 + px) * (1.0f / NW);
        const float dyf = fminf(fmaxf(gy + off0, 0.0f), 0.99999f);
        const float dxf = fminf(fmaxf(gx + off1, 0.0f), 0.99999f);
        const int dy = (int)floorf(dyf * (float)NDH);
        const int dx = (int)floorf(dxf * (float)NDW);
        const int cell = dy * NDW + dx;

        meta[b * NHW + pixbase + px] = ((u32)cell << 16) | (u32)f32_to_bf16_rn(att);
        atts[b * NHW + pixbase + px] = att;

        const int o1 = OUT1_BASE + b * 2 * NHW + pixbase + px;
        out[o1]       = off0;
        out[o1 + NHW] = off1;
    }
}

// ============================================================================
// K2: per-batch attention histogram. One block per b (32 blocks, 1024 thr).
// Writes iasum = 1/(sum_att_per_cell + eps).
// ============================================================================
__global__ __launch_bounds__(1024) void k_asum(
    const u32* __restrict__ meta, const float* __restrict__ atts,
    float* __restrict__ iasum)
{
    __shared__ float as_[NCELLS];   // 16 KB

    const int t = threadIdx.x;
    const int b = blockIdx.x;

    #pragma unroll
    for (int j = 0; j < 4; ++j) as_[t + 1024 * j] = 0.f;
    __syncthreads();

    #pragma unroll
    for (int j = 0; j < 16; ++j) {
        const int p = t + 1024 * j;
        atomicAdd(&as_[meta[b * NHW + p] >> 16], atts[b * NHW + p]);
    }
    __syncthreads();

    #pragma unroll
    for (int j = 0; j < 4; ++j) {
        const int i = t + 1024 * j;
        iasum[b * NCELLS + i] = 1.0f / (as_[i] + EPSF);
    }
}

// ============================================================================
// K3: single-phase streaming gather + dest write. One block per (b,c),
// 256 threads, LDS = acc[4096] only (16 KB => ~8 blocks/CU, 32 waves).
// Pixel loop: load x float4 (HBM) + meta uint4 (L2-hot) -> write dest float4
// -> per-quad run-length merge -> 1..4 LDS atomicAdd into acc.
// Epilogue: out = acc * iasum, coalesced.
// ============================================================================
__global__ __launch_bounds__(256) void k_gd(
    const float* __restrict__ x, const u32* __restrict__ meta,
    const float* __restrict__ iasum, float* __restrict__ out)
{
    __shared__ float acc[NCELLS];  // 16 KB

    const int t   = threadIdx.x;
    const int blk = blockIdx.x;
    const int b   = blk >> 8;
    const int c   = blk & 255;

    float4* acc4 = reinterpret_cast<float4*>(acc);
    const float4 z4 = make_float4(0.f, 0.f, 0.f, 0.f);
    #pragma unroll
    for (int k = 0; k < 4; ++k) acc4[t + 256 * k] = z4;
    __syncthreads();

    const float4* xp4  = reinterpret_cast<const float4*>(x + (size_t)(b * NC + c) * NHW);
    const uint4*  mt4  = reinterpret_cast<const uint4*>(meta + (size_t)b * NHW);
    float4* dst4 = reinterpret_cast<float4*>(out + OUT2_BASE + (size_t)(b * NC + c) * NHW);
    const int basec = (b * NC + c) * NCELLS;

    #pragma unroll 4
    for (int k = 0; k < 16; ++k) {
        const int idx = t + 256 * k;         // float4 index; pixels idx*4..+3
        const float4 xv = xp4[idx];
        const uint4  mm = mt4[idx];

        const int c0 = (int)(mm.x >> 16), c1 = (int)(mm.y >> 16);
        const int c2 = (int)(mm.z >> 16), c3 = (int)(mm.w >> 16);

        // destination write (pure VMEM stream, rides with the x stream)
        float4 dv;
        dv.x = (float)(basec + c0);
        dv.y = (float)(basec + c1);
        dv.z = (float)(basec + c2);
        dv.w = (float)(basec + c3);
        dst4[idx] = dv;

        const float v0 = xv.x * __uint_as_float(mm.x << 16);
        const float v1 = xv.y * __uint_as_float(mm.y << 16);
        const float v2 = xv.z * __uint_as_float(mm.z << 16);
        const float v3 = xv.w * __uint_as_float(mm.w << 16);

        // per-quad run-length merge: 1..4 atomics instead of always 4
        float s = v0;
        int cur = c0;
        if (c1 == cur) s += v1; else { atomicAdd(&acc[cur], s); cur = c1; s = v1; }
        if (c2 == cur) s += v2; else { atomicAdd(&acc[cur], s); cur = c2; s = v2; }
        if (c3 == cur) s += v3; else { atomicAdd(&acc[cur], s); cur = c3; s = v3; }
        atomicAdd(&acc[cur], s);
    }
    __syncthreads();

    // epilogue: normalized out write
    const float4* ia4 = reinterpret_cast<const float4*>(iasum + b * NCELLS);
    float4* ob4 = reinterpret_cast<float4*>(out + (size_t)(b * NC + c) * NCELLS);
    #pragma unroll
    for (int k = 0; k < 4; ++k) {
        float4 a = acc4[t + 256 * k];
        const float4 sv = ia4[t + 256 * k];
        a.x *= sv.x;
        a.y *= sv.y;
        a.z *= sv.z;
        a.w *= sv.w;
        ob4[t + 256 * k] = a;
    }
}

extern "C" void kernel_launch(void* const* d_in, const int* in_sizes, int n_in,
                              void* d_out, int out_size, void* d_ws, size_t ws_size,
                              hipStream_t stream)
{
    (void)in_sizes; (void)n_in; (void)out_size; (void)ws_size;
    const float* x  = (const float*)d_in[0];
    const float* cw = (const float*)d_in[1];
    const float* cb = (const float*)d_in[2];
    float* out = (float*)d_out;
    char*  ws  = (char*)d_ws;

    u32*   meta  = (u32*)  (ws + WS_META);
    float* atts  = (float*)(ws + WS_ATTS);
    float* iasum = (float*)(ws + WS_IASUM);

    k_cells<<<dim3(NB * 256), dim3(256),  0, stream>>>(x, cw, cb, out, meta, atts);
    k_asum <<<dim3(NB),       dim3(1024), 0, stream>>>(meta, atts, iasum);
    k_gd   <<<dim3(NB * NC),  dim3(256),  0, stream>>>(x, meta, iasum, out);
}

// Round 9
// 585.801 us; speedup vs baseline: 1.3634x; 1.3634x over previous
//
#include <hip/hip_runtime.h>
#include <math.h>

// Problem constants (B,C,H,W) = (32,256,128,128), downsample 0.5 -> (64,64)
#define NB 32
#define NC 256
#define NH 128
#define NW 128
#define NDH 64
#define NDW 64
#define NHW (NH * NW)          // 16384
#define NCELLS (NDH * NDW)     // 4096
#define OUT0_N (NB * NC * NCELLS)       // out: 33,554,432 floats
#define OUT1_BASE OUT0_N
#define OUT1_N (NB * 2 * NHW)           // offset: 1,048,576 floats
#define OUT2_BASE (OUT1_BASE + OUT1_N)  // destination: 134,217,728 floats

#define EPSF 1e-5f

typedef unsigned short u16;
typedef unsigned int   u32;

// ---- workspace layout (bytes), 16B-aligned; total ~7.5 MB ----
#define WS_CELLS   ((size_t)0)                       // u16  [NB*NHW]    1 MB
#define WS_ATTS    (WS_CELLS + (size_t)NB*NHW*2)     // f32  [NB*NHW]    2 MB
#define WS_ENTS    (WS_ATTS + (size_t)NB*NHW*4)      // uint2[NB*NHW]    4 MB  {cell<<16|pix, att}
#define WS_IASUM   (WS_ENTS + (size_t)NB*NHW*8)      // f32  [NB*NCELLS] 512 KB

// async global->LDS DMA, 16 bytes per lane (global_load_lds_dwordx4)
__device__ __forceinline__ void async_stage16(const float* g, float* l) {
    __builtin_amdgcn_global_load_lds(
        (const __attribute__((address_space(1))) unsigned int*)g,
        (__attribute__((address_space(3))) unsigned int*)l,
        16, 0, 0);
}

// ============================================================================
// K1: conv stream (R4-proven). One block = 64 consecutive pixels of one image.
// Reads x once; emits offset output, destination output, cells, atts.
// ============================================================================
__global__ __launch_bounds__(256) void k_conv(
    const float* __restrict__ x, const float* __restrict__ cw,
    const float* __restrict__ cb, float* __restrict__ out,
    u16* __restrict__ cells, float* __restrict__ atts)
{
    __shared__ float cwS[3][NC];
    __shared__ float red[256][13];
    __shared__ int   cellv[64];

    const int t    = threadIdx.x;
    const int blk  = blockIdx.x;
    const int b    = blk >> 8;
    const int tile = blk & 255;
    const int h    = tile >> 1;
    const int w0   = (tile & 1) << 6;
    const int pixbase = h * NW + w0;

    cwS[0][t] = cw[t];
    cwS[1][t] = cw[NC + t];
    cwS[2][t] = cw[2 * NC + t];
    __syncthreads();

    const int ct = t >> 4;            // channel group 0..15
    const int pg = (t & 15) << 2;     // pixel quad base 0..60
    const float* xb = x + (size_t)b * NC * NHW + pixbase + pg;

    float p00 = 0, p01 = 0, p02 = 0;
    float p10 = 0, p11 = 0, p12 = 0;
    float p20 = 0, p21 = 0, p22 = 0;
    float p30 = 0, p31 = 0, p32 = 0;

    #pragma unroll
    for (int i = 0; i < 16; ++i) {
        const int c = (i << 4) + ct;
        const float4 xv = *reinterpret_cast<const float4*>(xb + (size_t)c * NHW);
        const float wc0 = cwS[0][c], wc1 = cwS[1][c], wc2 = cwS[2][c];
        p00 += xv.x * wc0; p01 += xv.x * wc1; p02 += xv.x * wc2;
        p10 += xv.y * wc0; p11 += xv.y * wc1; p12 += xv.y * wc2;
        p20 += xv.z * wc0; p21 += xv.z * wc1; p22 += xv.z * wc2;
        p30 += xv.w * wc0; p31 += xv.w * wc1; p32 += xv.w * wc2;
    }

    red[t][0]  = p00; red[t][1]  = p01; red[t][2]  = p02;
    red[t][3]  = p10; red[t][4]  = p11; red[t][5]  = p12;
    red[t][6]  = p20; red[t][7]  = p21; red[t][8]  = p22;
    red[t][9]  = p30; red[t][10] = p31; red[t][11] = p32;
    __syncthreads();

    if (t < 64) {
        const int px   = t;
        const int row0 = px >> 2;
        const int col  = (px & 3) * 3;
        float s0 = 0, s1 = 0, s2 = 0;
        #pragma unroll
        for (int j = 0; j < 16; ++j) {
            const int r = row0 + (j << 4);
            s0 += red[r][col];
            s1 += red[r][col + 1];
            s2 += red[r][col + 2];
        }
        const float off0 = s0 + cb[0];
        const float off1 = s1 + cb[1];
        const float att  = expf(s2 + cb[2]);

        const float gy = (float)h * (1.0f / NH);
        const float gx = (float)(w0 + px) * (1.0f / NW);
        const float dyf = fminf(fmaxf(gy + off0, 0.0f), 0.99999f);
        const float dxf = fminf(fmaxf(gx + off1, 0.0f), 0.99999f);
        const int dy = (int)floorf(dyf * (float)NDH);
        const int dx = (int)floorf(dxf * (float)NDW);
        const int cell = dy * NDW + dx;

        cellv[px] = cell;
        cells[b * NHW + pixbase + px] = (u16)cell;
        atts [b * NHW + pixbase + px] = att;

        const int o1 = OUT1_BASE + b * 2 * NHW + pixbase + px;
        out[o1]       = off0;
        out[o1 + NHW] = off1;
    }
    __syncthreads();

    // destination output: dest[b,c,pix] = (b*C+c)*NCELLS + cell[pix]
    const int  c0 = cellv[pg], c1 = cellv[pg + 1], c2 = cellv[pg + 2], c3 = cellv[pg + 3];
    float* __restrict__ dst = out + OUT2_BASE;
    #pragma unroll
    for (int i = 0; i < 16; ++i) {
        const int c = (i << 4) + ct;
        const int basec = (b * NC + c) * NCELLS;
        float4 dv;
        dv.x = (float)(basec + c0);
        dv.y = (float)(basec + c1);
        dv.z = (float)(basec + c2);
        dv.w = (float)(basec + c3);
        *reinterpret_cast<float4*>(dst + (size_t)(b * NC + c) * NHW + pixbase + pg) = dv;
    }
}

// ============================================================================
// K2: per-batch counting sort (R4-proven simple-atomic version), emitting
// uint2 entries {cell<<16|pix, f32 att} and iasum = 1/(att_sum+eps).
// ============================================================================
__global__ __launch_bounds__(1024) void k_sort(
    const u16* __restrict__ cells, const float* __restrict__ atts,
    uint2* __restrict__ ents, float* __restrict__ iasum)
{
    __shared__ u32   hist[NCELLS];
    __shared__ float as_[NCELLS];
    __shared__ u32   ts[1024];

    const int t = threadIdx.x;
    const int b = blockIdx.x;
    const u16*   cb_ = cells + b * NHW;
    const float* ab_ = atts + b * NHW;

    #pragma unroll
    for (int j = 0; j < 4; ++j) { hist[t + 1024 * j] = 0u; as_[t + 1024 * j] = 0.f; }
    __syncthreads();

    #pragma unroll
    for (int j = 0; j < 16; ++j) {
        const int p  = t + 1024 * j;
        const int cl = cb_[p];
        atomicAdd(&hist[cl], 1u);
        atomicAdd(&as_[cl], ab_[p]);
    }
    __syncthreads();

    const u32 h0 = hist[4 * t], h1 = hist[4 * t + 1], h2 = hist[4 * t + 2], h3 = hist[4 * t + 3];
    const u32 T  = h0 + h1 + h2 + h3;
    ts[t] = T;
    __syncthreads();
    for (int off = 1; off < 1024; off <<= 1) {
        const u32 v = (t >= off) ? ts[t - off] : 0u;
        __syncthreads();
        ts[t] += v;
        __syncthreads();
    }
    const u32 base = ts[t] - T;
    hist[4 * t]     = base;
    hist[4 * t + 1] = base + h0;
    hist[4 * t + 2] = base + h0 + h1;
    hist[4 * t + 3] = base + h0 + h1 + h2;

    #pragma unroll
    for (int j = 0; j < 4; ++j) {
        const int i = t + 1024 * j;
        iasum[b * NCELLS + i] = 1.0f / (as_[i] + EPSF);
    }
    __syncthreads();

    #pragma unroll
    for (int j = 0; j < 16; ++j) {
        const int p  = t + 1024 * j;
        const int cl = cb_[p];
        const u32 pos = atomicAdd(&hist[cl], 1u);
        ents[b * NHW + pos] = make_uint2(((u32)cl << 16) | (u32)p,
                                         __float_as_uint(ab_[p]));
    }
}

// ============================================================================
// K3: gather. One block per (b,c), 256 threads. LDS: raw f32 x-plane (64 KB,
// staged via global_load_lds DMA — zero VALU) + f32 acc (16 KB) = 80 KB =>
// 2 blocks/CU; one block's DMA overlaps the other's gather (VALU+LDS only).
// Gather: 64 sorted uint2 entries/thread in 4 independent run-length streams;
// att is applied per entry from the entry word (f32, exact). Epilogue:
// out = acc * iasum, coalesced.
// ============================================================================
#define ENT(EX, EY, CUR, S)                                                   \
    {                                                                         \
        const int   cl_ = (int)((EX) >> 16);                                  \
        const float v_  = xpl[(EX) & 0xFFFFu] * __uint_as_float(EY);          \
        if (cl_ != (CUR)) { atomicAdd(&acc[(CUR)], (S)); (S) = 0.f; (CUR) = cl_; } \
        (S) += v_;                                                            \
    }

__global__ __launch_bounds__(256) void k_gd(
    const float* __restrict__ x, const uint2* __restrict__ ents,
    const float* __restrict__ iasum, float* __restrict__ out)
{
    __shared__ float xpl[NHW];     // 64 KB f32 x-plane
    __shared__ float acc[NCELLS];  // 16 KB

    const int t    = threadIdx.x;
    const int blk  = blockIdx.x;
    const int b    = blk >> 8;
    const int c    = blk & 255;
    const int wave = t >> 6;
    const int lane = t & 63;

    // Issue the DMA staging first: 16 wave-level global_load_lds_dwordx4,
    // lane-linear (wave-uniform LDS base + lane*16), no VGPR round-trip.
    const float* xp = x + (size_t)(b * NC + c) * NHW;
    #pragma unroll
    for (int k = 0; k < 16; ++k) {
        const int vec = (k * 4 + wave) * 64 + lane;   // float4 slot 0..4095
        async_stage16(xp + vec * 4, &xpl[vec * 4]);
    }

    // Zero acc while the DMA is in flight.
    float4* acc4 = reinterpret_cast<float4*>(acc);
    const float4 z4 = make_float4(0.f, 0.f, 0.f, 0.f);
    #pragma unroll
    for (int k = 0; k < 4; ++k) acc4[t + 256 * k] = z4;

    __syncthreads();   // compiler drains vmcnt+lgkmcnt before s_barrier

    // 4 independent run-length streams of 16 entries each.
    {
        const uint2* el = ents + b * NHW + t * 64;
        float s0 = 0.f, s1 = 0.f, s2 = 0.f, s3 = 0.f;
        int   c0 = (int)(el[0].x  >> 16);
        int   c1 = (int)(el[16].x >> 16);
        int   c2 = (int)(el[32].x >> 16);
        int   c3 = (int)(el[48].x >> 16);

        #pragma unroll
        for (int i = 0; i < 8; ++i) {
            const uint4 q0 = *reinterpret_cast<const uint4*>(el + 0  + i * 2);
            const uint4 q1 = *reinterpret_cast<const uint4*>(el + 16 + i * 2);
            const uint4 q2 = *reinterpret_cast<const uint4*>(el + 32 + i * 2);
            const uint4 q3 = *reinterpret_cast<const uint4*>(el + 48 + i * 2);
            ENT(q0.x, q0.y, c0, s0); ENT(q0.z, q0.w, c0, s0);
            ENT(q1.x, q1.y, c1, s1); ENT(q1.z, q1.w, c1, s1);
            ENT(q2.x, q2.y, c2, s2); ENT(q2.z, q2.w, c2, s2);
            ENT(q3.x, q3.y, c3, s3); ENT(q3.z, q3.w, c3, s3);
        }
        atomicAdd(&acc[c0], s0);
        atomicAdd(&acc[c1], s1);
        atomicAdd(&acc[c2], s2);
        atomicAdd(&acc[c3], s3);
    }
    __syncthreads();

    // Epilogue: normalized coalesced write.
    const float4* ia4 = reinterpret_cast<const float4*>(iasum + b * NCELLS);
    float4* ob4 = reinterpret_cast<float4*>(out + (size_t)(b * NC + c) * NCELLS);
    #pragma unroll
    for (int k = 0; k < 4; ++k) {
        float4 a = acc4[t + 256 * k];
        const float4 sv = ia4[t + 256 * k];
        a.x *= sv.x;
        a.y *= sv.y;
        a.z *= sv.z;
        a.w *= sv.w;
        ob4[t + 256 * k] = a;
    }
}

extern "C" void kernel_launch(void* const* d_in, const int* in_sizes, int n_in,
                              void* d_out, int out_size, void* d_ws, size_t ws_size,
                              hipStream_t stream)
{
    (void)in_sizes; (void)n_in; (void)out_size; (void)ws_size;
    const float* x  = (const float*)d_in[0];
    const float* cw = (const float*)d_in[1];
    const float* cb = (const float*)d_in[2];
    float* out = (float*)d_out;
    char*  ws  = (char*)d_ws;

    u16*   cells = (u16*)  (ws + WS_CELLS);
    float* atts  = (float*)(ws + WS_ATTS);
    uint2* ents  = (uint2*)(ws + WS_ENTS);
    float* iasum = (float*)(ws + WS_IASUM);

    k_conv<<<dim3(NB * 256), dim3(256),  0, stream>>>(x, cw, cb, out, cells, atts);
    k_sort<<<dim3(NB),       dim3(1024), 0, stream>>>(cells, atts, ents, iasum);
    k_gd  <<<dim3(NB * NC),  dim3(256),  0, stream>>>(x, ents, iasum, out);
}